// Round 6
// baseline (116.080 us; speedup 1.0000x reference)
//
#include <hip/hip_runtime.h>
#include <math.h>
#include <utility>

// AllPassMORR circulant conv2d, MI355X.
// x: [8,32,64,64] f32, weight: [8,36,8] f32, scale: [19] f32
// out: [8,64,64,64] f32
//
// out[b,p*8+t,ho,wo] = sum_q (-D*scale_q) / (C2 - K2*cos(2*pi*ph_rev))
//   ph_rev = sum_s xsq[q*8+s] * |w|[p,q,(t-s)&7] / (2*pi)  (w pre-scaled)
// K2=2AR, C2=1+(AR)^2, D=(1-A^2)(1-R^2); constant "1" of tr cancels since
// scale = concat(s,-s) sums to zero.
//
// R6: occupancy was structurally capped at 16 waves/CU (1 thread per
// (pixel,p)). Split the q-sum in half across lane-pairs (l, l^32): 512
// blocks x 1024 thr = 32 waves/CU = 8 waves/SIMD; combine with
// __shfl_xor(32). x-tile restrided to [32][10][40]: row-stride 40 == 8
// (mod 32 banks) puts the wave's 4 rows on disjoint bank quartets for
// every kw offset -> minimum 2-lane/bank (free), zero conflicts.

template <class F, size_t... I>
__device__ __forceinline__ void sf_impl(F&& f, std::index_sequence<I...>) {
    (f(std::integral_constant<size_t, I>{}), ...);
}
template <size_t N, class F>
__device__ __forceinline__ void static_for(F&& f) {
    sf_impl(f, std::make_index_sequence<N>{});
}

__global__ __launch_bounds__(1024, 8)
void morr_kernel(const float* __restrict__ xg, const float* __restrict__ wg,
                 const float* __restrict__ sg, float* __restrict__ out) {
    __shared__ __align__(16) float lds_x[32 * 10 * 40];   // 51200 B
    __shared__ __align__(16) float lds_w[8 * 36 * 8];     // 9216 B
    __shared__ float lds_nds[36];

    constexpr double Ad = 0.987, Rd = 0.99;
    constexpr float K2 = (float)(2.0 * Ad * Rd);
    constexpr float C2 = (float)(1.0 + (Ad * Rd) * (Ad * Rd));
    constexpr float D  = (float)((1.0 - Ad * Ad) * (1.0 - Rd * Rd));
    constexpr float INV2PI = 0.15915494309189535f;

    const int tid = threadIdx.x;
    const int b   = blockIdx.z;
    const int gr0 = blockIdx.y * 8;     // 8 row-tiles of 8
    const int gc0 = blockIdx.x * 8;     // 8 col-tiles of 8

    // ---- stage squared input tile 32ch x 10x10 halo, stride-40 rows ----
    for (int i = tid; i < 3200; i += 1024) {
        int c = i / 100, rem = i - c * 100;
        int r = rem / 10, cl = rem - r * 10;
        int gr = gr0 - 1 + r, gc = gc0 - 1 + cl;
        float v = 0.f;
        if ((unsigned)gr < 64u && (unsigned)gc < 64u)
            v = xg[((b * 32 + c) * 64 + gr) * 64 + gc];
        lds_x[c * 400 + r * 40 + cl] = v * v;
    }
    // ---- stage |weight|/(2*pi)  (phase in revolutions for v_cos_f32) ----
    for (int i = tid; i < 2304; i += 1024) lds_w[i] = fabsf(wg[i]) * INV2PI;
    // ---- stage -D*scale (differential rails, even-q branch) ----
    if (tid < 36) {
        float sv = (tid < 18) ? sg[tid] : -sg[tid - 18];
        lds_nds[tid] = -D * sv;
    }
    __syncthreads();

    // tid = p*128 + pxh*64 + qh*32 + pxl ; wave-uniform: p, pxh
    const int p   = tid >> 7;            // 0..7
    const int pxh = (tid >> 6) & 1;      // row-half of tile
    const int qh  = (tid >> 5) & 1;      // q-half (cb 0-1 vs 2-3)
    const int pxl = tid & 31;
    const int row = pxh * 4 + (pxl >> 3);   // 0..7
    const int col = pxl & 7;                // 0..7

    const float* __restrict__ xb = &lds_x[row * 40 + col];
    const float* __restrict__ wp = &lds_w[p * 288];

    float acc[8];
    static_for<8>([&](auto T) { acc[T] = 0.f; });

    for (int cbl = 0; cbl < 2; ++cbl) {          // this thread's 2 ch-blocks
        const int cb = qh * 2 + cbl;             // 0..3
        const float* __restrict__ xcb = xb + cb * 3200;   // 8 ch * 400
        const float* __restrict__ wcb = wp + cb * 72;
        const float* __restrict__ ncb = &lds_nds[cb * 9];

        static_for<9>([&](auto QQ) {
            constexpr int qq = QQ;
            float xq[8];
            static_for<8>([&](auto S) {
                constexpr int s   = S;
                constexpr int u   = qq * 8 + s;     // 0..71 within cb
                constexpr int off = (u / 9) * 400 + ((u % 9) / 3) * 40 + (u % 3);
                xq[s] = xcb[off];
            });
            const float nds = ncb[qq];
            const float4 wa = *reinterpret_cast<const float4*>(wcb + qq * 8);
            const float4 wz = *reinterpret_cast<const float4*>(wcb + qq * 8 + 4);
            const float wv[8] = {wa.x, wa.y, wa.z, wa.w, wz.x, wz.y, wz.z, wz.w};

            static_for<8>([&](auto T) {
                constexpr int t = T;
                float ph = xq[0] * wv[t];           // revolutions
                static_for<7>([&](auto S) {
                    constexpr int s = (int)S + 1;
                    ph = fmaf(xq[s], wv[(t - s + 8) & 7], ph);
                });
                float cv  = __builtin_amdgcn_cosf(ph);   // cos(2*pi*ph)
                float den = fmaf(-K2, cv, C2);
                float inv = __builtin_amdgcn_rcpf(den);
                acc[t] = fmaf(nds, inv, acc[t]);
            });
        });
    }

    // ---- combine q-halves (partner = lane ^ 32) ----
    float accF[8];
    static_for<8>([&](auto T) {
        constexpr int t = T;
        accF[t] = acc[t] + __shfl_xor(acc[t], 32);
    });

    // ---- epilogue: qh=0 lanes write t 0..3, qh=1 lanes write t 4..7 ----
    const int gr = gr0 + row, gc = gc0 + col;
    static_for<4>([&](auto TT) {
        constexpr int tt = TT;
        const int t  = (qh << 2) + tt;
        const int oc = p * 8 + t;
        out[(b * 64 + oc) * 4096 + gr * 64 + gc] = accF[t];
    });
}

extern "C" void kernel_launch(void* const* d_in, const int* in_sizes, int n_in,
                              void* d_out, int out_size, void* d_ws, size_t ws_size,
                              hipStream_t stream) {
    const float* x = (const float*)d_in[0];
    const float* w = (const float*)d_in[1];
    const float* s = (const float*)d_in[2];
    float* out = (float*)d_out;
    dim3 grid(8, 8, 8);   // (col-tiles, row-tiles, batch)
    dim3 block(1024);
    hipLaunchKernelGGL(morr_kernel, grid, block, 0, stream, x, w, s, out);
}

// Round 8
// 93.654 us; speedup vs baseline: 1.2395x; 1.2395x over previous
//
#include <hip/hip_runtime.h>
#include <math.h>
#include <utility>

// AllPassMORR circulant conv2d, MI355X.
// x: [8,32,64,64] f32, weight: [8,36,8] f32, scale: [19] f32
// out: [8,64,64,64] f32
//
// out[b,p*8+t,ho,wo] = -D * sum_q sgn_q*s_q / (C2 - K2*cos(2*pi*ph_rev))
//   ph_rev = sum_s (xsq[q*8+s]/2pi) * |w|[p,q,(t-s)&7]   (1/2pi folded into x^2)
// K2=2AR, C2=1+(AR)^2, D=(1-A^2)(1-R^2); constant "1" of tr cancels since
// scale rail = concat(s,-s) sums to zero.
//
// R7: R6 spilled (FETCH 89MB / WRITE 163MB scratch) because 64-VGPR cap <
// need. Fix: weights live in SGPRs -- q-split moved to whole waves
// (qh wave-uniform via readfirstlane) so |w| loads are scalar s_loads from
// global (abs = scalar AND, +-rail = scalar XOR of sign bit, -D in epilogue).
// Deletes wv[] VGPRs, lds_w, and all weight ds_reads. Epilogue exchange is
// fully static-indexed via a 16KB LDS union (no rule-#20 scratch).

template <class F, size_t... I>
__device__ __forceinline__ void sf_impl(F&& f, std::index_sequence<I...>) {
    (f(std::integral_constant<size_t, I>{}), ...);
}
template <size_t N, class F>
__device__ __forceinline__ void static_for(F&& f) {
    sf_impl(f, std::make_index_sequence<N>{});
}

__global__ __launch_bounds__(1024, 8)
void morr_kernel(const float* __restrict__ xg, const float* __restrict__ wg,
                 const float* __restrict__ sg, float* __restrict__ out) {
    __shared__ union {
        float x[32 * 10 * 40];      // 51200 B squared-input tile (stride-40 rows)
        float ex[2][4][8][64];      // 16 KB cross-wave partial-sum exchange
    } sm;

    constexpr double Ad = 0.987, Rd = 0.99;
    constexpr float K2 = (float)(2.0 * Ad * Rd);
    constexpr float C2 = (float)(1.0 + (Ad * Rd) * (Ad * Rd));
    constexpr float D  = (float)((1.0 - Ad * Ad) * (1.0 - Rd * Rd));
    constexpr float INV2PI = 0.15915494309189535f;

    const int tid = threadIdx.x;
    const int b   = blockIdx.z;
    const int gr0 = blockIdx.y * 8;     // 8 row-tiles of 8
    const int gc0 = blockIdx.x * 8;     // 8 col-tiles of 8

    // ---- stage x^2/(2*pi) tile, 32ch x 10x10 halo, stride-40 rows ----
    // row-stride 40 == 8 mod 32 banks -> rows {0..3} and {4..7} tile the 32
    // banks disjointly => uniform 2-way (free) for every kernel offset.
    for (int i = tid; i < 3200; i += 1024) {
        int c = i / 100, rem = i - c * 100;
        int r = rem / 10, cl = rem - r * 10;
        int gr = gr0 - 1 + r, gc = gc0 - 1 + cl;
        float v = 0.f;
        if ((unsigned)gr < 64u && (unsigned)gc < 64u)
            v = xg[((b * 32 + c) * 64 + gr) * 64 + gc];
        sm.x[c * 400 + r * 40 + cl] = v * v * INV2PI;
    }
    __syncthreads();

    // tid = p(3b) | qh(1b) | px(6b): each wave has uniform (p, qh).
    const int px  = tid & 63;
    const int qhu = __builtin_amdgcn_readfirstlane((tid >> 6) & 1);  // q-half
    const int p   = __builtin_amdgcn_readfirstlane(tid >> 7);        // 0..7
    const int row = px >> 3;            // 0..7
    const int col = px & 7;             // 0..7

    const float* __restrict__ xb = &sm.x[row * 40 + col];
    // uniform bases -> scalar loads
    const unsigned* __restrict__ wp =
        reinterpret_cast<const unsigned*>(wg) + p * 288 + qhu * 144;
    const unsigned* __restrict__ sp = reinterpret_cast<const unsigned*>(sg);
    const unsigned sgnbit = ((unsigned)qhu) << 31;   // negate rail for q>=18

    float acc[8];
    static_for<8>([&](auto T) { acc[T] = 0.f; });

    static_for<2>([&](auto CBL) {
        constexpr int cbl = CBL;                       // cb = qhu*2 + cbl
        const float* __restrict__ xcb = xb + (qhu * 2 + cbl) * 3200;
        static_for<9>([&](auto QQ) {
            constexpr int qq = QQ;
            // 8 unfold elements, constexpr ds offsets
            float xq[8];
            static_for<8>([&](auto S) {
                constexpr int s   = S;
                constexpr int u   = qq * 8 + s;        // 0..71 within cb
                constexpr int off = (u / 9) * 400 + ((u % 9) / 3) * 40 + (u % 3);
                xq[s] = xcb[off];
            });
            // |w| row: uniform -> s_load_dwordx8 + s_and (stays in SGPRs)
            float wv[8];
            static_for<8>([&](auto J) {
                constexpr int j = J;
                wv[j] = __uint_as_float(wp[cbl * 72 + qq * 8 + j] & 0x7fffffffu);
            });
            // signed rail value: uniform s_load + scalar xor
            const float sv = __uint_as_float(sp[cbl * 9 + qq] ^ sgnbit);

            static_for<8>([&](auto T) {
                constexpr int t = T;
                float ph = xq[0] * wv[t];              // revolutions
                static_for<7>([&](auto S) {
                    constexpr int s = (int)S + 1;
                    ph = fmaf(xq[s], wv[(t - s + 8) & 7], ph);
                });
                float cv  = __builtin_amdgcn_cosf(ph); // cos(2*pi*ph)
                float den = fmaf(-K2, cv, C2);
                float inv = __builtin_amdgcn_rcpf(den);
                acc[t] = fmaf(sv, inv, acc[t]);
            });
        });
    });

    // ---- cross-wave combine: partner wave = same (p,px), qh flipped ----
    __syncthreads();                     // done reading sm.x (union reuse)
    if (qhu == 0) {
        static_for<4>([&](auto J) { sm.ex[0][J][p][px] = acc[4 + (int)J]; });
    } else {
        static_for<4>([&](auto J) { sm.ex[1][J][p][px] = acc[(int)J]; });
    }
    __syncthreads();

    const int gr = gr0 + row, gc = gc0 + col;
    if (qhu == 0) {
        static_for<4>([&](auto J) {
            constexpr int j = J;
            float v = acc[j] + sm.ex[1][j][p][px];
            out[((b * 64 + p * 8 + j) * 64 + gr) * 64 + gc] = -D * v;
        });
    } else {
        static_for<4>([&](auto J) {
            constexpr int j = J;
            float v = acc[4 + j] + sm.ex[0][j][p][px];
            out[((b * 64 + p * 8 + 4 + j) * 64 + gr) * 64 + gc] = -D * v;
        });
    }
}

extern "C" void kernel_launch(void* const* d_in, const int* in_sizes, int n_in,
                              void* d_out, int out_size, void* d_ws, size_t ws_size,
                              hipStream_t stream) {
    const float* x = (const float*)d_in[0];
    const float* w = (const float*)d_in[1];
    const float* s = (const float*)d_in[2];
    float* out = (float*)d_out;
    dim3 grid(8, 8, 8);   // (col-tiles, row-tiles, batch)
    dim3 block(1024);
    hipLaunchKernelGGL(morr_kernel, grid, block, 0, stream, x, w, s, out);
}

// Round 10
// 92.179 us; speedup vs baseline: 1.2593x; 1.0160x over previous
//
#include <hip/hip_runtime.h>
#include <math.h>
#include <utility>

// AllPassMORR circulant conv2d, MI355X.
// x: [8,32,64,64] f32, weight: [8,36,8] f32, scale: [19] f32
// out: [8,64,64,64] f32
//
// out[b,p*8+t,ho,wo] = -D*K2 * sum_{qp<18} s_qp * (c1-c2) / (a*b)
//   a = C2-K2*cos(2pi*ph[qp]), b = C2-K2*cos(2pi*ph[qp+18])  (rail pairing:
//   s*(1/a - 1/b) = s*K2*(c1-c2)/(ab) -- one rcp per pair, error-neutral)
//   ph[q] = sum_s (x^2/2pi)[q*8+s] * |w|[p,q,(t-s)&7]
// K2=2AR, C2=1+(AR)^2, D=(1-A^2)(1-R^2); constant "1" of tr cancels (rails).
//
// R9: R5 (41.5us) is ~90% VALU-pipe-saturated at 4 waves/SIMD (R7's 8-wave
// q-split = null). Cut pipe cycles: rail-pairing removes 144 of 288 rcp;
// t-split threads (1 px x 1 p x 4 t) give 2 blocks/CU with NO combine;
// weights/scale in SGPRs via uniform s_loads (th-rotation folded into the
// scalar load address: index j ^ (th*4)).

template <class F, size_t... I>
__device__ __forceinline__ void sf_impl(F&& f, std::index_sequence<I...>) {
    (f(std::integral_constant<size_t, I>{}), ...);
}
template <size_t N, class F>
__device__ __forceinline__ void static_for(F&& f) {
    sf_impl(f, std::make_index_sequence<N>{});
}

__global__ __launch_bounds__(1024, 8)
void morr_kernel(const float* __restrict__ xg, const float* __restrict__ wg,
                 const float* __restrict__ sg, float* __restrict__ out) {
    // squared-input tile [32ch][10r][stride 40]: base banks row*8+col cover
    // all 32 banks exactly twice per wave -> minimal 2-way (free), and all
    // compute-read offsets are constexpr adds (permutation preserved).
    __shared__ __align__(16) float smx[32 * 10 * 40];   // 51200 B

    constexpr double Ad = 0.987, Rd = 0.99;
    constexpr float K2  = (float)(2.0 * Ad * Rd);
    constexpr float C2  = (float)(1.0 + (Ad * Rd) * (Ad * Rd));
    constexpr float NDK = (float)(-(1.0 - Ad * Ad) * (1.0 - Rd * Rd) * (2.0 * Ad * Rd));
    constexpr float INV2PI = 0.15915494309189535f;

    const int tid = threadIdx.x;
    const int b   = blockIdx.z;
    const int gr0 = blockIdx.y * 8;     // 8 row-tiles of 8
    const int gc0 = blockIdx.x * 8;     // 8 col-tiles of 8

    // ---- stage x^2/(2*pi), 32ch x 10x10 halo ----
    for (int i = tid; i < 3200; i += 1024) {
        int c = i / 100, rem = i - c * 100;
        int r = rem / 10, cl = rem - r * 10;
        int gr = gr0 - 1 + r, gc = gc0 - 1 + cl;
        float v = 0.f;
        if ((unsigned)gr < 64u && (unsigned)gc < 64u)
            v = xg[((b * 32 + c) * 64 + gr) * 64 + gc];
        smx[c * 400 + r * 40 + cl] = v * v * INV2PI;
    }
    __syncthreads();

    // tid = p(3b) | th(1b) | px(6b); p, th wave-uniform.
    const int px  = tid & 63;
    const int th4 = __builtin_amdgcn_readfirstlane(((tid >> 6) & 1) * 4); // t-base
    const int p   = __builtin_amdgcn_readfirstlane(tid >> 7);             // 0..7
    const int row = px >> 3;            // 0..7
    const int col = px & 7;             // 0..7

    const float* __restrict__ xb = &smx[row * 40 + col];
    const unsigned* __restrict__ wgu =
        reinterpret_cast<const unsigned*>(wg) + p * 288;   // uniform base

    float acc[4];
    static_for<4>([&](auto J) { acc[J] = 0.f; });

    static_for<18>([&](auto QP) {
        constexpr int qp = QP;
        // unfold elements for q=qp and partner q=qp+18 (ci offset +144 =
        // exactly +16 channels -> LDS offset +6400)
        float xl[8], xh[8];
        static_for<8>([&](auto S) {
            constexpr int s   = S;
            constexpr int u   = qp * 8 + s;     // 0..143
            constexpr int off = (u / 9) * 400 + ((u % 9) / 3) * 40 + (u % 3);
            xl[s] = xb[off];
            xh[s] = xb[off + 6400];
        });
        // |w| rows, pre-rotated by th4 (uniform scalar loads; j ^ th4 = (j+th4)&7)
        float wl[8], wh[8];
        static_for<8>([&](auto Jw) {
            constexpr int j = Jw;
            wl[j] = __uint_as_float(wgu[qp * 8 + (j ^ th4)] & 0x7fffffffu);
            wh[j] = __uint_as_float(wgu[144 + qp * 8 + (j ^ th4)] & 0x7fffffffu);
        });
        const float sv = sg[qp];                // uniform scalar

        static_for<4>([&](auto J) {
            constexpr int t = J;                // actual tap = th4 + J (rotated)
            float p1 = xl[0] * wl[t];
            float p2 = xh[0] * wh[t];
            static_for<7>([&](auto S) {
                constexpr int s = (int)S + 1;
                p1 = fmaf(xl[s], wl[(t - s + 8) & 7], p1);
                p2 = fmaf(xh[s], wh[(t - s + 8) & 7], p2);
            });
            float c1 = __builtin_amdgcn_cosf(p1);   // cos(2*pi*rev)
            float c2 = __builtin_amdgcn_cosf(p2);
            float a  = fmaf(-K2, c1, C2);
            float bb = fmaf(-K2, c2, C2);
            float rr = __builtin_amdgcn_rcpf(a * bb);
            acc[J] = fmaf(sv, (c1 - c2) * rr, acc[J]);
        });
    });

    // ---- epilogue: out[b, p*8 + th4 + J, gr, gc] = NDK * acc[J] ----
    const int gr = gr0 + row, gc = gc0 + col;
    static_for<4>([&](auto J) {
        constexpr int j = J;
        const int oc = p * 8 + th4 + j;
        out[((b * 64 + oc) * 64 + gr) * 64 + gc] = NDK * acc[j];
    });
}

extern "C" void kernel_launch(void* const* d_in, const int* in_sizes, int n_in,
                              void* d_out, int out_size, void* d_ws, size_t ws_size,
                              hipStream_t stream) {
    const float* x = (const float*)d_in[0];
    const float* w = (const float*)d_in[1];
    const float* s = (const float*)d_in[2];
    float* out = (float*)d_out;
    dim3 grid(8, 8, 8);   // (col-tiles, row-tiles, batch)
    dim3 block(1024);
    hipLaunchKernelGGL(morr_kernel, grid, block, 0, stream, x, w, s, out);
}